// Round 14
// baseline (51.362 us; speedup 1.0000x reference)
//
#include <hip/hip_runtime.h>

#define THREADS 256
#define NB 2048            // grid-stride block count: 2048 blocks * 4 waves = 8192 wave slots
#define ROW_LEN 512

typedef float f4  __attribute__((ext_vector_type(4)));
typedef char  c8  __attribute__((ext_vector_type(8)));
typedef char  c16 __attribute__((ext_vector_type(16)));

__device__ __forceinline__ float wave_reduce_max(float v) {
#pragma unroll
    for (int o = 32; o > 0; o >>= 1) v = fmaxf(v, __shfl_xor(v, o));
    return v;
}
__device__ __forceinline__ float wave_reduce_sum(float v) {
#pragma unroll
    for (int o = 32; o > 0; o >>= 1) v += __shfl_xor(v, o);
    return v;
}

// PLA-exp for one element; edges/coeffs from LDS. Exact searchsorted:
// fused uniform-width guess + correction against the true edge table.
__device__ __forceinline__ float pla_eval(float xv, float mx,
                                          const float* s_a, const float2* s_mc) {
    float sh = xv - mx;                     // <= 0; |sh| < 32 for this input
    float t  = rintf(sh * 67108864.0f);     // Q32.26 snap (2^31 clamp never binds)
    float fx = t * 1.4901161193847656e-8f;  // * 2^-26 exact
    float xc = fmaxf(fx, -10.0f);           // fx <= 0 structurally
    int gi = (int)fmaf(xc, 1.2f, 12.0f);    // guess in [0,12]; trunc of -5e-7 -> 0
    gi = min(gi, 11);
    if (xc < s_a[gi])            gi -= 1;
    else if (xc >= s_a[gi + 1])  gi += 1;
    int idx = min(gi, 10);                  // reference clamp to len-2
    float2 p = s_mc[idx];
    return fmaf(p.x, xc, p.y);
}

#define MAX8(x) fmaxf(fmaxf(fmaxf(x[0], x[1]), fmaxf(x[2], x[3])), \
                      fmaxf(fmaxf(x[4], x[5]), fmaxf(x[6], x[7])))

// ---------------- fast path: 2 adjacent rows per wave, TRIPS compile-time ----------
// svq16 layout: pair p, lane l -> bytes {qA[8], qB[8]} at svq16[p*64+l] (16 B/lane).
// rowg2[p] = {gA, gB}. Self-consistent with pla_pass1_pair.
template <int TRIPS>
__global__ __launch_bounds__(THREADS) void pla_pass0_pair(
    const float* __restrict__ scores,
    const float* __restrict__ coeffs_m,
    const float* __restrict__ coeffs_c,
    const float* __restrict__ intervals,
    c16* __restrict__ svq16,
    float2* __restrict__ rowg2,
    float* __restrict__ slots)
{
    __shared__ float2 s_mc[12];
    __shared__ float  s_a[13];
    __shared__ float  s_bm[4];

    const int tid = threadIdx.x;
    if (tid < 12) {
        s_mc[tid] = make_float2(coeffs_m[tid], coeffs_c[tid]);
        s_a[tid]  = intervals[tid];
    }
    if (tid == 12) s_a[12] = __builtin_inff();
    __syncthreads();

    const int wave = tid >> 6;
    const int lane = tid & 63;
    const float c10 = coeffs_c[10];
    const float k0  = 127.0f / c10;

    float bmax = 0.0f;

#pragma unroll
    for (int t = 0; t < TRIPS; ++t) {
        const int pair = (blockIdx.x + t * NB) * 4 + wave;   // rows 2p, 2p+1
        const f4* rp = reinterpret_cast<const f4*>(scores + (size_t)pair * 2 * ROW_LEN);
        f4 a0 = rp[lane], a1 = rp[lane + 64];                // row A
        f4 b0 = rp[lane + 128], b1 = rp[lane + 192];         // row B
        float xa[8] = {a0.x, a0.y, a0.z, a0.w, a1.x, a1.y, a1.z, a1.w};
        float xb[8] = {b0.x, b0.y, b0.z, b0.w, b1.x, b1.y, b1.z, b1.w};

        float mxa = MAX8(xa), mxb = MAX8(xb);
        // two independent 6-step chains interleave per-instruction
#pragma unroll
        for (int o = 32; o > 0; o >>= 1) {
            mxa = fmaxf(mxa, __shfl_xor(mxa, o));
            mxb = fmaxf(mxb, __shfl_xor(mxb, o));
        }

        float suma = 0.0f, sumb = 0.0f;
        c16 q;
#pragma unroll
        for (int j = 0; j < 8; ++j) {
            float ev = pla_eval(xa[j], mxa, s_a, s_mc);
            suma += ev;
            q[j] = (char)(int)rintf(ev * k0);
        }
#pragma unroll
        for (int j = 0; j < 8; ++j) {
            float ev = pla_eval(xb[j], mxb, s_a, s_mc);
            sumb += ev;
            q[8 + j] = (char)(int)rintf(ev * k0);
        }
        svq16[(size_t)pair * 64 + lane] = q;                 // 16 B/lane, 1 KB/wave

#pragma unroll
        for (int o = 32; o > 0; o >>= 1) {
            suma += __shfl_xor(suma, o);
            sumb += __shfl_xor(sumb, o);
        }
        const float ia = 1.0f / (suma + 1e-9f);
        const float ib = 1.0f / (sumb + 1e-9f);
        if (lane == 0) {
            rowg2[pair] = make_float2(c10 * ia * (1.0f / 127.0f),
                                      c10 * ib * (1.0f / 127.0f));
            bmax = fmaxf(bmax, fmaxf(c10 * ia, c10 * ib));
        }
    }

    if (lane == 0) s_bm[wave] = bmax;
    __syncthreads();
    if (tid == 0) {
        slots[blockIdx.x] = fmaxf(fmaxf(s_bm[0], s_bm[1]), fmaxf(s_bm[2], s_bm[3]));
    }
}

template <int TRIPS>
__global__ __launch_bounds__(THREADS) void pla_pass1_pair(
    const c16* __restrict__ svq16,
    const float2* __restrict__ rowg2,
    const float* __restrict__ slots,
    float* __restrict__ out)
{
    __shared__ float s_red[4];
    const int tid  = threadIdx.x;
    const int wave = tid >> 6;
    const int lane = tid & 63;

    float m = 0.0f;
    for (int i = tid; i < NB; i += THREADS) m = fmaxf(m, slots[i]);
    m = wave_reduce_max(m);
    if (lane == 0) s_red[wave] = m;
    __syncthreads();
    const float am = fmaxf(fmaxf(s_red[0], s_red[1]), fmaxf(s_red[2], s_red[3]));

    const float scale  = fmaxf(am * (1.0f / 127.0f), 1e-8f);
    const float iscale = 1.0f / scale;

#pragma unroll
    for (int t = 0; t < TRIPS; ++t) {
        const int pair = (blockIdx.x + t * NB) * 4 + wave;
        c16 a = svq16[(size_t)pair * 64 + lane];
        float2 gg = rowg2[pair];
        const float fA = gg.x * iscale;
        const float fB = gg.y * iscale;

        float oA[8], oB[8];
#pragma unroll
        for (int j = 0; j < 8; ++j) {
            oA[j] = fminf(fmaxf(rintf((float)a[j]     * fA), -127.0f), 127.0f) * scale;
            oB[j] = fminf(fmaxf(rintf((float)a[8 + j] * fB), -127.0f), 127.0f) * scale;
        }
        f4* op = reinterpret_cast<f4*>(out + (size_t)pair * 2 * ROW_LEN);
        f4 wA0 = {oA[0], oA[1], oA[2], oA[3]};
        f4 wA1 = {oA[4], oA[5], oA[6], oA[7]};
        f4 wB0 = {oB[0], oB[1], oB[2], oB[3]};
        f4 wB1 = {oB[4], oB[5], oB[6], oB[7]};
        __builtin_nontemporal_store(wA0, op + lane);
        __builtin_nontemporal_store(wA1, op + lane + 64);
        __builtin_nontemporal_store(wB0, op + lane + 128);
        __builtin_nontemporal_store(wB1, op + lane + 192);
    }
}

// ---------------- generic fallback (round-13 logic, 1 row/wave, linear c8) --------
__global__ __launch_bounds__(THREADS) void pla_pass0_gen(
    const float* __restrict__ scores,
    const float* __restrict__ coeffs_m,
    const float* __restrict__ coeffs_c,
    const float* __restrict__ intervals,
    char* __restrict__ svq,
    float* __restrict__ rowg,
    float* __restrict__ slots,
    int nrows)
{
    __shared__ float2 s_mc[12];
    __shared__ float  s_a[13];
    __shared__ float  s_bm[4];

    const int tid = threadIdx.x;
    if (tid < 12) {
        s_mc[tid] = make_float2(coeffs_m[tid], coeffs_c[tid]);
        s_a[tid]  = intervals[tid];
    }
    if (tid == 12) s_a[12] = __builtin_inff();
    __syncthreads();

    const int wave = tid >> 6;
    const int lane = tid & 63;
    const float c10 = coeffs_c[10];
    const float k0  = 127.0f / c10;
    float bmax = 0.0f;

    const int ngroups = (nrows + 3) / 4;
    for (int g = blockIdx.x; g < ngroups; g += NB) {
        const int row = g * 4 + wave;
        if (row >= nrows) continue;

        const f4* rp = reinterpret_cast<const f4*>(scores + (size_t)row * ROW_LEN);
        f4 v0 = rp[lane], v1 = rp[lane + 64];
        float x[8] = {v0.x, v0.y, v0.z, v0.w, v1.x, v1.y, v1.z, v1.w};

        float mx = MAX8(x);
        mx = wave_reduce_max(mx);

        float sum = 0.0f;
        c8 q;
#pragma unroll
        for (int j = 0; j < 8; ++j) {
            float ev = pla_eval(x[j], mx, s_a, s_mc);
            sum += ev;
            q[j] = (char)(int)rintf(ev * k0);
        }
        reinterpret_cast<c8*>(svq + (size_t)row * ROW_LEN)[lane] = q;

        sum = wave_reduce_sum(sum);
        const float inv = 1.0f / (sum + 1e-9f);
        if (lane == 0) {
            rowg[row] = c10 * inv * (1.0f / 127.0f);
            bmax = fmaxf(bmax, c10 * inv);
        }
    }

    if (lane == 0) s_bm[wave] = bmax;
    __syncthreads();
    if (tid == 0)
        slots[blockIdx.x] = fmaxf(fmaxf(s_bm[0], s_bm[1]), fmaxf(s_bm[2], s_bm[3]));
}

__global__ __launch_bounds__(THREADS) void pla_pass1_gen(
    const char* __restrict__ svq,
    const float* __restrict__ rowg,
    const float* __restrict__ slots,
    float* __restrict__ out,
    int nrows)
{
    __shared__ float s_red[4];
    const int tid  = threadIdx.x;
    const int wave = tid >> 6;
    const int lane = tid & 63;

    float m = 0.0f;
    for (int i = tid; i < NB; i += THREADS) m = fmaxf(m, slots[i]);
    m = wave_reduce_max(m);
    if (lane == 0) s_red[wave] = m;
    __syncthreads();
    const float am = fmaxf(fmaxf(s_red[0], s_red[1]), fmaxf(s_red[2], s_red[3]));

    const float scale  = fmaxf(am * (1.0f / 127.0f), 1e-8f);
    const float iscale = 1.0f / scale;

    const int ngroups = (nrows + 3) / 4;
    for (int g = blockIdx.x; g < ngroups; g += NB) {
        const int row = g * 4 + wave;
        if (row >= nrows) continue;

        const float f = rowg[row] * iscale;
        c8 a = reinterpret_cast<const c8*>(svq + (size_t)row * ROW_LEN)[lane];

        float o[8];
#pragma unroll
        for (int j = 0; j < 8; ++j) {
            float q = fminf(fmaxf(rintf((float)a[j] * f), -127.0f), 127.0f);
            o[j] = q * scale;
        }
        f4* op = reinterpret_cast<f4*>(out + (size_t)row * ROW_LEN);
        f4 w0 = {o[0], o[1], o[2], o[3]};
        f4 w1 = {o[4], o[5], o[6], o[7]};
        __builtin_nontemporal_store(w0, op + lane);
        __builtin_nontemporal_store(w1, op + lane + 64);
    }
}

extern "C" void kernel_launch(void* const* d_in, const int* in_sizes, int n_in,
                              void* d_out, int out_size, void* d_ws, size_t ws_size,
                              hipStream_t stream) {
    const float* scores    = (const float*)d_in[0];
    const float* coeffs_m  = (const float*)d_in[1];
    const float* coeffs_c  = (const float*)d_in[2];
    const float* intervals = (const float*)d_in[3];
    float* out = (float*)d_out;

    const int nrows = in_sizes[0] / ROW_LEN;

    // ws layout (all regions fully overwritten every launch):
    //   [0, NB*4)            slots
    //   [128KB, ...)         rowg (generic: float/row) or rowg2 (fast: float2/pair)
    //   [1MB, +nrows*512)    svq (s8, ~25 MB; fast path reads/writes as c16 pairs)
    float*  slots = (float*)d_ws;
    float*  rowg  = (float*)((char*)d_ws + (128 << 10));
    float2* rowg2 = (float2*)((char*)d_ws + (128 << 10));
    char*   svq   = (char*)d_ws + (1 << 20);
    c16*    svq16 = (c16*)svq;

    // Fast path: nrows = 49152 -> pairs/block-trip = 4, trips = 3, no remainder.
    const bool fast = (nrows % 8 == 0) && ((nrows / 8) % NB == 0) && ((nrows / 8) / NB == 3);

    if (fast) {
        pla_pass0_pair<3><<<NB, THREADS, 0, stream>>>(
            scores, coeffs_m, coeffs_c, intervals, svq16, rowg2, slots);
        pla_pass1_pair<3><<<NB, THREADS, 0, stream>>>(svq16, rowg2, slots, out);
    } else {
        pla_pass0_gen<<<NB, THREADS, 0, stream>>>(
            scores, coeffs_m, coeffs_c, intervals, svq, rowg, slots, nrows);
        pla_pass1_gen<<<NB, THREADS, 0, stream>>>(svq, rowg, slots, out, nrows);
    }
}